// Round 3
// baseline (792.243 us; speedup 1.0000x reference)
//
#include <hip/hip_runtime.h>

typedef __bf16 bf16x8 __attribute__((ext_vector_type(8)));
typedef float f32x4 __attribute__((ext_vector_type(4)));

#define ROW_F 1029            // floats per x row
#define SLAB_STRIDE 36        // floats per slab row: 144 B (16B-aligned, 2-way banks)

// ---------------- contention row means ----------------
__global__ __launch_bounds__(256) void k_rowmean(const float* __restrict__ cont,
                                                 float* __restrict__ rowmean) {
    __shared__ float red[4];
    int row = blockIdx.x;
    const float4* cr = (const float4*)(cont + (size_t)row * 1024);
    float4 v = cr[threadIdx.x];
    float p = v.x + v.y + v.z + v.w;
    for (int m = 1; m < 64; m <<= 1) p += __shfl_xor(p, m, 64);
    int lane = threadIdx.x & 63, wid = threadIdx.x >> 6;
    if (lane == 0) red[wid] = p;
    __syncthreads();
    if (threadIdx.x == 0)
        rowmean[row] = (red[0] + red[1] + red[2] + red[3]) * (1.0f / 1024.0f);
}

// ---------------- pack w_eff into MFMA B-fragment order ----------------
// w_eff[k] = w1[k] (k<4), w1[k+1] (4<=k<1028), 0 (k>=1028).  K padded to 1056.
// Layout: [(kb*4 + ntile)*64 + lane]*8 + j -> B[k = kb*32 + (lane>>4)*8 + j][n = ntile*16 + (lane&15)]
__global__ __launch_bounds__(256) void k_wpack(const float* __restrict__ w1,
                                               __bf16* __restrict__ wfrag) {
    int o = blockIdx.x * 256 + threadIdx.x;     // grid sized exactly 67584
    int j    = o & 7;
    int lane = (o >> 3) & 63;
    int nt   = (o >> 9) & 3;
    int kb   = o >> 11;
    int k = kb * 32 + ((lane >> 4) << 3) + j;
    int n = nt * 16 + (lane & 15);
    float val = 0.0f;
    if (k < 4)          val = w1[k * 64 + n];
    else if (k < 1028)  val = w1[(k + 1) * 64 + n];
    wfrag[o] = (__bf16)val;
}

// ---------------- main fused kernel ----------------
// Wave-synchronous: each wave owns 16 rows, a private f32 slab (coalesced
// global -> LDS transpose), fused exact-f32 argmax, MFMA h1, wave-local MLP tail.
__global__ __launch_bounds__(256) void k_main(const float* __restrict__ x,
                                              const float* __restrict__ w1,
                                              const float* __restrict__ b1,
                                              const float* __restrict__ w2,
                                              const float* __restrict__ b2,
                                              const float* __restrict__ w3,
                                              const float* __restrict__ b3,
                                              const float* __restrict__ rowmean,
                                              const __bf16* __restrict__ wfrag,
                                              float* __restrict__ out) {
    __shared__ __align__(16) float slab_s[4][16 * SLAB_STRIDE];   // 2304 B / wave
    __shared__ float h1_s[4][16 * 65];                            // 4160 B / wave

    const int tid  = threadIdx.x;
    const int l    = tid & 63;
    const int w    = tid >> 6;
    const int m0   = l & 15;          // consume: row within wave tile
    const int c    = l >> 4;          // consume: k-partition 0..3
    const int c32  = l & 31;          // stage: column within kb chunk
    const int hsel = l >> 5;          // stage: row parity within pair

    float* slabw = slab_s[w];
    float* h1w   = h1_s[w];

    const int rowbase = blockIdx.x * 64 + w * 16;
    const float* xw = x + (size_t)rowbase * ROW_F;
    const f32x4* wfp = (const f32x4*)wfrag;

    f32x4 acc0 = {0.f,0.f,0.f,0.f}, acc1 = {0.f,0.f,0.f,0.f};
    f32x4 acc2 = {0.f,0.f,0.f,0.f}, acc3 = {0.f,0.f,0.f,0.f};
    float best = -1e30f; int bidx = 4; float dens = 0.f;

    // preload kb = 0 (coalesced: each instr = 2 contiguous 128 B row-segments)
    float vx[8];
    #pragma unroll
    for (int i = 0; i < 8; ++i)
        vx[i] = __builtin_nontemporal_load(xw + (size_t)(2*i + hsel) * ROW_F + c32);

    for (int kb = 0; kb < 33; ++kb) {
        // ---- prefetch kb+1 ----
        float vn[8];
        if (kb < 31) {
            #pragma unroll
            for (int i = 0; i < 8; ++i)
                vn[i] = __builtin_nontemporal_load(xw + (size_t)(2*i + hsel) * ROW_F + (kb + 1) * 32 + c32);
        } else if (kb == 31) {
            // kb=32 chunk: only cols 1024..1028 exist; zero-fill the rest
            #pragma unroll
            for (int i = 0; i < 8; ++i)
                vn[i] = (c32 < 5)
                    ? __builtin_nontemporal_load(xw + (size_t)(2*i + hsel) * ROW_F + 1024 + c32)
                    : 0.0f;
        }

        // ---- stage kb into wave-private slab (2-way banks: (4*row + col) % 32) ----
        #pragma unroll
        for (int i = 0; i < 8; ++i)
            slabw[(2*i + hsel) * SLAB_STRIDE + c32] = vx[i];

        // ---- consume kb: A-fragment from slab (16B-aligned ds_read_b128 x2) ----
        const f32x4* afp = (const f32x4*)(slabw + m0 * SLAB_STRIDE + c * 8);
        f32x4 a0 = afp[0], a1 = afp[1];
        float vj[8];
        #pragma unroll
        for (int jj = 0; jj < 4; ++jj) { vj[jj] = a0[jj]; vj[4 + jj] = a1[jj]; }
        bf16x8 af;
        #pragma unroll
        for (int j = 0; j < 8; ++j) af[j] = (__bf16)vj[j];

        // ---- fused exact-f32 argmax over k in [4, 1028) ----
        if (kb == 0) {
            if (c == 0) dens = vj[0];
            #pragma unroll
            for (int j = 0; j < 8; ++j) {
                int k = c * 8 + j;
                bool ok = (k >= 4) && (vj[j] > best);
                best = ok ? vj[j] : best;
                bidx = ok ? k : bidx;
            }
        } else if (kb == 32) {
            if (c == 0) {
                #pragma unroll
                for (int j = 0; j < 4; ++j) {
                    bool gt = vj[j] > best;
                    best = gt ? vj[j] : best;
                    bidx = gt ? (1024 + j) : bidx;
                }
            }
        } else {
            int kbase = kb * 32 + c * 8;
            #pragma unroll
            for (int j = 0; j < 8; ++j) {
                bool gt = vj[j] > best;
                best = gt ? vj[j] : best;
                bidx = gt ? (kbase + j) : bidx;
            }
        }

        // ---- 4 MFMAs (B-fragments coalesced from L2-resident wfrag) ----
        acc0 = __builtin_amdgcn_mfma_f32_16x16x32_bf16(af, __builtin_bit_cast(bf16x8, wfp[(kb*4 + 0)*64 + l]), acc0, 0,0,0);
        acc1 = __builtin_amdgcn_mfma_f32_16x16x32_bf16(af, __builtin_bit_cast(bf16x8, wfp[(kb*4 + 1)*64 + l]), acc1, 0,0,0);
        acc2 = __builtin_amdgcn_mfma_f32_16x16x32_bf16(af, __builtin_bit_cast(bf16x8, wfp[(kb*4 + 2)*64 + l]), acc2, 0,0,0);
        acc3 = __builtin_amdgcn_mfma_f32_16x16x32_bf16(af, __builtin_bit_cast(bf16x8, wfp[(kb*4 + 3)*64 + l]), acc3, 0,0,0);

        #pragma unroll
        for (int i = 0; i < 8; ++i) vx[i] = vn[i];
    }

    // ---- reduce (best,bidx) across the 4 k-partitions sharing a row ----
    #pragma unroll
    for (int off = 16; off < 64; off <<= 1) {
        float ob = __shfl_xor(best, off, 64);
        int   oi = __shfl_xor(bidx, off, 64);
        if (ob > best || (ob == best && oi < bidx)) { best = ob; bidx = oi; }
    }
    float ce = 0.f;
    if (c == 0) ce = rowmean[bidx - 4] * dens;    // lanes 0..15 hold ce for rows 0..15
    float ce_r[4];
    #pragma unroll
    for (int r = 0; r < 4; ++r) ce_r[r] = __shfl(ce, c * 4 + r, 64);

    // ---- epilogue: h1 = relu(acc + ce*w1[4,:] + b1) -> wave-private LDS ----
    {
        const f32x4* accs[4] = {&acc0, &acc1, &acc2, &acc3};
        #pragma unroll
        for (int nt = 0; nt < 4; ++nt) {
            int n = nt * 16 + m0;
            float w14 = w1[4 * 64 + n];
            float bb  = b1[n];
            #pragma unroll
            for (int r = 0; r < 4; ++r) {
                int m = c * 4 + r;
                float hv = (*accs[nt])[r] + ce_r[r] * w14 + bb;
                h1w[m * 65 + n] = fmaxf(hv, 0.0f);
            }
        }
    }

    // ---- layers 2 and 3, wave-local (16 rows, 4 sweeps of 4 rows) ----
    {
        int s  = l & 15;
        int n2 = s * 2;
        #pragma unroll
        for (int it = 0; it < 4; ++it) {
            int r2 = it * 4 + c;
            float a0 = b2[n2], a1 = b2[n2 + 1];
            const float* hrow = &h1w[r2 * 65];
            #pragma unroll 8
            for (int k = 0; k < 64; ++k) {
                float hv = hrow[k];                               // LDS broadcast
                float2 wv = *(const float2*)(w2 + k * 32 + n2);   // L1-resident
                a0 = fmaf(hv, wv.x, a0);
                a1 = fmaf(hv, wv.y, a1);
            }
            a0 = fmaxf(a0, 0.f); a1 = fmaxf(a1, 0.f);
            float p = a0 * w3[n2] + a1 * w3[n2 + 1];
            p += __shfl_xor(p, 1, 64);
            p += __shfl_xor(p, 2, 64);
            p += __shfl_xor(p, 4, 64);
            p += __shfl_xor(p, 8, 64);
            if (s == 0) out[rowbase + r2] = fmaxf(p + b3[0], 0.f);
        }
    }
}

extern "C" void kernel_launch(void* const* d_in, const int* in_sizes, int n_in,
                              void* d_out, int out_size, void* d_ws, size_t ws_size,
                              hipStream_t stream) {
    const float* x    = (const float*)d_in[0];
    const float* cont = (const float*)d_in[1];
    const float* w1   = (const float*)d_in[2];
    const float* b1   = (const float*)d_in[3];
    const float* w2   = (const float*)d_in[4];
    const float* b2   = (const float*)d_in[5];
    const float* w3   = (const float*)d_in[6];
    const float* b3   = (const float*)d_in[7];

    __bf16* wfrag   = (__bf16*)d_ws;                     // 67584 bf16 = 135168 B
    float*  rowmean = (float*)((char*)d_ws + 135168);    // 1024 f32

    int B = in_sizes[0] / ROW_F;                         // 131072
    float* out = (float*)d_out;

    hipLaunchKernelGGL(k_rowmean, dim3(1024),   dim3(256), 0, stream, cont, rowmean);
    hipLaunchKernelGGL(k_wpack,   dim3(264),    dim3(256), 0, stream, w1, wfrag);
    hipLaunchKernelGGL(k_main,    dim3(B / 64), dim3(256), 0, stream,
                       x, w1, b1, w2, b2, w3, b3, rowmean, wfrag, out);
}